// Round 16
// baseline (1313.451 us; speedup 1.0000x reference)
//
#include <hip/hip_runtime.h>
#include <hip/hip_bf16.h>

// ---------------------------------------------------------------------------
// Phase 1a: CSR build by dst, then gather-aggregate
// ---------------------------------------------------------------------------

__global__ __launch_bounds__(256) void sge_count(
    const int* __restrict__ dst, int* __restrict__ cnt, int nE) {
  int e = blockIdx.x * 256 + threadIdx.x;
  if (e >= nE) return;
  atomicAdd(&cnt[dst[e]], 1);
}

__global__ __launch_bounds__(256) void sge_blocksum(
    const int* __restrict__ cnt, int* __restrict__ bsum, int N) {
  int i = blockIdx.x * 256 + threadIdx.x;
  int v = (i < N) ? cnt[i] : 0;
#pragma unroll
  for (int o = 1; o < 64; o <<= 1) v += __shfl_xor(v, o);
  __shared__ int ws[4];
  int lane = threadIdx.x & 63, wid = threadIdx.x >> 6;
  if (lane == 0) ws[wid] = v;
  __syncthreads();
  if (threadIdx.x == 0)
    bsum[blockIdx.x] = ws[0] + ws[1] + ws[2] + ws[3];
}

__global__ __launch_bounds__(64) void sge_scan_top(
    int* __restrict__ bsum, int* __restrict__ offs, int nb, int N, int nE) {
  int lane = threadIdx.x;
  int carry = 0;
  for (int base = 0; base < nb; base += 64) {
    int i = base + lane;
    int v = (i < nb) ? bsum[i] : 0;
    int s = v;
#pragma unroll
    for (int o = 1; o < 64; o <<= 1) {
      int t = __shfl_up(s, o);
      if (lane >= o) s += t;
    }
    if (i < nb) bsum[i] = carry + s - v;  // exclusive
    carry += __shfl(s, 63);
  }
  if (lane == 0) offs[N] = nE;
}

__global__ __launch_bounds__(256) void sge_scan_block(
    const int* __restrict__ cnt, const int* __restrict__ bsum,
    int* __restrict__ offs, int* __restrict__ pos, int N) {
  int i = blockIdx.x * 256 + threadIdx.x;
  int v = (i < N) ? cnt[i] : 0;
  int lane = threadIdx.x & 63, wid = threadIdx.x >> 6;
  int s = v;
#pragma unroll
  for (int o = 1; o < 64; o <<= 1) {
    int t = __shfl_up(s, o);
    if (lane >= o) s += t;
  }
  __shared__ int ws[4];
  if (lane == 63) ws[wid] = s;
  __syncthreads();
  int wbase = 0;
  for (int w = 0; w < wid; ++w) wbase += ws[w];
  if (i < N) {
    int o = bsum[blockIdx.x] + wbase + s - v;
    offs[i] = o;
    pos[i] = o;
  }
}

__global__ __launch_bounds__(256) void sge_fill(
    const int* __restrict__ src, const int* __restrict__ dst,
    int* __restrict__ pos, int* __restrict__ sorted_src, int nE) {
  int e = blockIdx.x * 256 + threadIdx.x;
  if (e >= nE) return;
  int p = atomicAdd(&pos[dst[e]], 1);
  sorted_src[p] = src[e];
}

// 64 lanes per node, two 32-lane halves split the edge range
__global__ __launch_bounds__(256) void sge_gather(
    const float* __restrict__ x, const int* __restrict__ sorted_src,
    const int* __restrict__ offs, float* __restrict__ agg, int N) {
  int node = blockIdx.x * 4 + (threadIdx.x >> 6);
  int lane = threadIdx.x & 63;
  int h = lane >> 5;           // half 0/1
  int c4 = (lane & 31) << 2;   // float4 column offset
  if (node >= N) return;
  int e0 = offs[node], e1 = offs[node + 1];
  float4 A = {0.f, 0.f, 0.f, 0.f}, B = {0.f, 0.f, 0.f, 0.f};
  int e = e0 + h;              // this half's edges: e0+h, e0+h+2, ...
  for (; e + 2 < e1; e += 4) {
    int s0 = sorted_src[e];
    int s1 = sorted_src[e + 2];
    float4 v0 = *(const float4*)&x[(size_t)s0 * 128 + c4];
    float4 v1 = *(const float4*)&x[(size_t)s1 * 128 + c4];
    A.x += v0.x; A.y += v0.y; A.z += v0.z; A.w += v0.w;
    B.x += v1.x; B.y += v1.y; B.z += v1.z; B.w += v1.w;
  }
  if (e < e1) {
    float4 v0 = *(const float4*)&x[(size_t)sorted_src[e] * 128 + c4];
    A.x += v0.x; A.y += v0.y; A.z += v0.z; A.w += v0.w;
  }
  float4 S;
  S.x = A.x + B.x; S.y = A.y + B.y; S.z = A.z + B.z; S.w = A.w + B.w;
  S.x += __shfl_xor(S.x, 32);
  S.y += __shfl_xor(S.y, 32);
  S.z += __shfl_xor(S.z, 32);
  S.w += __shfl_xor(S.w, 32);
  if (h == 0) {
    float inv = 1.0f / fmaxf((float)(e1 - e0), 1.0f);
    float4 r;
    r.x = S.x * inv; r.y = S.y * inv; r.z = S.z * inv; r.w = S.w * inv;
    *(float4*)&agg[(size_t)node * 128 + c4] = r;
  }
}

// ---------------------------------------------------------------------------
// Phase 1b: z = agg @ W   [N,128]@[128,256] -> [N,256]
// ---------------------------------------------------------------------------
__global__ __launch_bounds__(256) void sge_gemm(
    const float* __restrict__ agg, const float* __restrict__ W,
    float* __restrict__ z) {
  __shared__ float xs[32][128];
  int n0 = blockIdx.x * 32;
  int t = threadIdx.x;
#pragma unroll
  for (int i = 0; i < 16; ++i) {
    int idx = t + i * 256;
    int r = idx >> 7;
    int c = idx & 127;
    xs[r][c] = agg[(long long)(n0 + r) * 128 + c];
  }
  __syncthreads();
  int wv = t >> 6, lane = t & 63;
  int r0 = wv * 8;
  float acc[8][4];
#pragma unroll
  for (int r = 0; r < 8; ++r)
#pragma unroll
    for (int q = 0; q < 4; ++q) acc[r][q] = 0.f;
  for (int k = 0; k < 128; k += 4) {
    float4 xv[8];
#pragma unroll
    for (int r = 0; r < 8; ++r) xv[r] = *(const float4*)&xs[r0 + r][k];
#pragma unroll
    for (int kk = 0; kk < 4; ++kk) {
      const float* Wr = W + (k + kk) * 256 + lane;
      float w0 = Wr[0], w1 = Wr[64], w2 = Wr[128], w3 = Wr[192];
#pragma unroll
      for (int r = 0; r < 8; ++r) {
        float xk = (kk == 0) ? xv[r].x
                 : (kk == 1) ? xv[r].y
                 : (kk == 2) ? xv[r].z : xv[r].w;
        acc[r][0] = fmaf(xk, w0, acc[r][0]);
        acc[r][1] = fmaf(xk, w1, acc[r][1]);
        acc[r][2] = fmaf(xk, w2, acc[r][2]);
        acc[r][3] = fmaf(xk, w3, acc[r][3]);
      }
    }
  }
#pragma unroll
  for (int r = 0; r < 8; ++r) {
    float* zr = z + (long long)(n0 + r0 + r) * 256 + lane;
#pragma unroll
    for (int q = 0; q < 4; ++q) zr[q * 64] = acc[r][q];
  }
}

// ---------------------------------------------------------------------------
// Phase 2 (v17): ONE wave per pair, TWO interleaved chains per wave:
//   chain A = roles {fab (own=0), gba (own=32)}: cols = opposite set,
//             E-exchange at rbA = own^32 (v14's wave-0 logic, verbatim).
//   chain B = roles {faa, gbb}: cols = own set, rbB = own (v14's wave-1).
// The two chains never communicate (v14 fact: the two waves of a pair only
// met at the final reduce). Shared row load xr + shared Nbuf. 2x in-wave
// ILP for the latency-bound softmin chain. Final-eps refresh via
// exp2(1.5625*log2(V)) (v11-validated). No __syncthreads in the loop.
// ---------------------------------------------------------------------------
template <int CTRL>
__device__ __forceinline__ float dpp_max(float x) {
  int r = __builtin_amdgcn_update_dpp(__float_as_int(x), __float_as_int(x),
                                      CTRL, 0xF, 0xF, false);
  return fmaxf(x, __int_as_float(r));
}
template <int CTRL>
__device__ __forceinline__ float dpp_add(float x) {
  int r = __builtin_amdgcn_update_dpp(0, __float_as_int(x), CTRL, 0xF, 0xF, true);
  return x + __int_as_float(r);
}
__device__ __forceinline__ float rdlane(float v, int lane) {
  return __int_as_float(__builtin_amdgcn_readlane(__float_as_int(v), lane));
}

__global__ __launch_bounds__(256, 4) void sge_energy(
    const float* __restrict__ z, const int* __restrict__ ep,
    const int* __restrict__ en, float* __restrict__ partial, int nP) {
  __shared__ __align__(16) float EbA[4][64];   // chain-A E per wave
  __shared__ __align__(16) float EbB[4][64];   // chain-B E per wave
  __shared__ __align__(16) float Nbuf[4][64];  // row norms per wave
  __shared__ float red[4];

  int t = threadIdx.x;
  int wv = t >> 6;        // wave in block = pair slot 0..3
  int l = t & 63;
  int row = l & 31;
  int own = l & 32;       // 0 = x-row half, 32 = y-row half

  int n2 = 2 * nP;
  int pair = blockIdx.x * 4 + wv;
  bool live = pair < n2;
  int pr = live ? pair : 0;
  bool isPos = pr < nP;
  int idx = isPos ? pr : pr - nP;
  const int* E = isPos ? ep : en;
  int na = E[idx], nb = E[idx + nP];

  // own row (shared by both chains)
  const float* zrow = z + (size_t)(own ? nb : na) * 256 + row * 8;
  float4 r0 = ((const float4*)zrow)[0];
  float4 r1 = ((const float4*)zrow)[1];
  float xr[8];
  xr[0] = r0.x; xr[1] = r0.y; xr[2] = r0.z; xr[3] = r0.w;
  xr[4] = r1.x; xr[5] = r1.y; xr[6] = r1.z; xr[7] = r1.w;

  float nself = xr[0] * xr[0];
  nself = fmaf(xr[1], xr[1], nself); nself = fmaf(xr[2], xr[2], nself);
  nself = fmaf(xr[3], xr[3], nself); nself = fmaf(xr[4], xr[4], nself);
  nself = fmaf(xr[5], xr[5], nself); nself = fmaf(xr[6], xr[6], nself);
  nself = fmaf(xr[7], xr[7], nself);
  Nbuf[wv][l] = nself;
  __builtin_amdgcn_wave_barrier();

  // chain A: cols = opposite set;  chain B: cols = own set
  const float4* zcA = (const float4*)(z + (size_t)(own ? na : nb) * 256);
  const float4* zcB = (const float4*)(z + (size_t)(own ? nb : na) * 256);
  int rbA = own ^ 32;
  int rbB = own;
  const float* NwA = Nbuf[wv] + rbA;
  const float* NwB = Nbuf[wv] + rbB;

  const float RLNE = 1.44269504088896340736f;  // log2(e)
  const float LN2 = 0.69314718055994530942f;
  const float LN32 = 3.46573590279972654709f;  // ln(32)
  const float K20 = RLNE / 10.0f;

  // build VA (cross matrix row) and VB (self matrix row); norm-form
  float VA[32], VB[32];
#pragma unroll
  for (int jq = 0; jq < 8; ++jq) {
    float4 njA = ((const float4*)NwA)[jq];
    float4 njB = ((const float4*)NwB)[jq];
#pragma unroll
    for (int k = 0; k < 4; ++k) {
      int j = jq * 4 + k;
      float4 a0 = zcA[2 * j];
      float4 a1 = zcA[2 * j + 1];
      float4 b0 = zcB[2 * j];
      float4 b1 = zcB[2 * j + 1];
      float dA = xr[0] * a0.x;
      float dB = xr[0] * b0.x;
      dA = fmaf(xr[1], a0.y, dA); dB = fmaf(xr[1], b0.y, dB);
      dA = fmaf(xr[2], a0.z, dA); dB = fmaf(xr[2], b0.z, dB);
      dA = fmaf(xr[3], a0.w, dA); dB = fmaf(xr[3], b0.w, dB);
      dA = fmaf(xr[4], a1.x, dA); dB = fmaf(xr[4], b1.x, dB);
      dA = fmaf(xr[5], a1.y, dA); dB = fmaf(xr[5], b1.y, dB);
      dA = fmaf(xr[6], a1.z, dA); dB = fmaf(xr[6], b1.z, dB);
      dA = fmaf(xr[7], a1.w, dA); dB = fmaf(xr[7], b1.w, dB);
      float nA = (k == 0) ? njA.x : (k == 1) ? njA.y : (k == 2) ? njA.z : njA.w;
      float nB = (k == 0) ? njB.x : (k == 1) ? njB.y : (k == 2) ? njB.z : njB.w;
      float sqA = fmaf(-2.0f, dA, nself + nA);
      float sqB = fmaf(-2.0f, dB, nself + nB);
      float CA = __builtin_amdgcn_sqrtf(fmaxf(sqA, 0.0f) + 1e-8f);
      float CB = __builtin_amdgcn_sqrtf(fmaxf(sqB, 0.0f) + 1e-8f);
      VA[j] = __builtin_amdgcn_exp2f(-CA * K20);
      VB[j] = __builtin_amdgcn_exp2f(-CB * K20);
    }
  }

  float* EA = EbA[wv];
  float* EB = EbB[wv];

  float PA = 0.0f, PB = 0.0f;
  float epsv = 10.0f;

#pragma unroll 1
  for (int it = 0; it < 9; ++it) {
    float eps = (it == 8) ? 0.05f : epsv;
    float k2 = RLNE / eps;
    float eln2 = eps * LN2;
    float c32 = eps * LN32;

    if (it == 8) {
      // eps 0.078125 -> 0.05: exponent scales by 1.5625 (v11-validated)
#pragma unroll
      for (int j = 0; j < 32; ++j) {
        VA[j] = __builtin_amdgcn_exp2f(1.5625f * __builtin_amdgcn_logf(VA[j]));
        VB[j] = __builtin_amdgcn_exp2f(1.5625f * __builtin_amdgcn_logf(VB[j]));
      }
    } else if (it > 0) {
#pragma unroll
      for (int j = 0; j < 32; ++j) {
        VA[j] *= VA[j];
        VB[j] *= VB[j];
      }
    }

    float mOwnA, mReadA, mOwnB;
    if (it >= 7) {
      float mA = PA, mB = PB;
      mA = dpp_max<0x111>(mA); mB = dpp_max<0x111>(mB);
      mA = dpp_max<0x112>(mA); mB = dpp_max<0x112>(mB);
      mA = dpp_max<0x114>(mA); mB = dpp_max<0x114>(mB);
      mA = dpp_max<0x118>(mA); mB = dpp_max<0x118>(mB);
      mA = dpp_max<0x142>(mA); mB = dpp_max<0x142>(mB);
      float gA0 = rdlane(mA, 31), gA1 = rdlane(mA, 63);
      float gB0 = rdlane(mB, 31), gB1 = rdlane(mB, 63);
      mOwnA = own ? gA1 : gA0;          // subtracted by writer
      mReadA = own ? gA0 : gA1;         // partner half's max (reader comp)
      mOwnB = own ? gB1 : gB0;          // self chain: read == own
    } else {
      mOwnA = mReadA = 0.0f;
      mOwnB = 0.0f;
    }

    EA[l] = __builtin_amdgcn_exp2f((PA - mOwnA) * k2);
    EB[l] = __builtin_amdgcn_exp2f((PB - mOwnB) * k2);
    __builtin_amdgcn_wave_barrier();

    float sA0 = 0.f, sA1 = 0.f, sA2 = 0.f, sA3 = 0.f;
    float sB0 = 0.f, sB1 = 0.f, sB2 = 0.f, sB3 = 0.f;
#pragma unroll
    for (int jq = 0; jq < 8; ++jq) {
      float4 EvA = ((const float4*)(EA + rbA))[jq];
      float4 EvB = ((const float4*)(EB + rbB))[jq];
      sA0 = fmaf(EvA.x, VA[4 * jq + 0], sA0);
      sB0 = fmaf(EvB.x, VB[4 * jq + 0], sB0);
      sA1 = fmaf(EvA.y, VA[4 * jq + 1], sA1);
      sB1 = fmaf(EvB.y, VB[4 * jq + 1], sB1);
      sA2 = fmaf(EvA.z, VA[4 * jq + 2], sA2);
      sB2 = fmaf(EvB.z, VB[4 * jq + 2], sB2);
      sA3 = fmaf(EvA.w, VA[4 * jq + 3], sA3);
      sB3 = fmaf(EvB.w, VB[4 * jq + 3], sB3);
    }
    float sA = fmaxf((sA0 + sA1) + (sA2 + sA3), 1e-37f);
    float sB = fmaxf((sB0 + sB1) + (sB2 + sB3), 1e-37f);
    __builtin_amdgcn_wave_barrier();  // reads done before next iter's writes

    PA = 0.5f * (PA + (c32 - mReadA - eln2 * __builtin_amdgcn_logf(sA)));
    PB = 0.5f * (PB + (c32 - mOwnB - eln2 * __builtin_amdgcn_logf(sB)));
    epsv *= 0.5f;
  }

  // wave sums: dA = sum(fab)+sum(gba), dB = sum(faa)+sum(gbb)
  float dA = PA, dB = PB;
  dA = dpp_add<0x111>(dA); dB = dpp_add<0x111>(dB);
  dA = dpp_add<0x112>(dA); dB = dpp_add<0x112>(dB);
  dA = dpp_add<0x114>(dA); dB = dpp_add<0x114>(dB);
  dA = dpp_add<0x118>(dA); dB = dpp_add<0x118>(dB);
  dA = dpp_add<0x142>(dA); dB = dpp_add<0x142>(dB);
  float sumA = rdlane(dA, 31) + rdlane(dA, 63);
  float sumB = rdlane(dB, 31) + rdlane(dB, 63);
  if (l == 0) {
    float term = 0.0f;
    if (live) {
      float e = (sumA - sumB) * (1.0f / 32.0f);
      if (isPos) {
        term = e * e;
      } else {
        float mm = fmaxf(1.0f - e, 0.0f);
        term = mm * mm;
      }
    }
    red[wv] = term;
  }
  __syncthreads();
  if (t == 0)
    partial[blockIdx.x] = (red[0] + red[1]) + (red[2] + red[3]);
}

// single-block final reduction: out = sum(partial) / nP
__global__ __launch_bounds__(1024) void sge_reduce(
    const float* __restrict__ partial, int n, float invnP,
    float* __restrict__ out) {
  __shared__ float ws[16];
  float s = 0.0f;
  for (int i = threadIdx.x; i < n; i += 1024) s += partial[i];
#pragma unroll
  for (int o = 1; o < 64; o <<= 1) s += __shfl_xor(s, o);
  if ((threadIdx.x & 63) == 0) ws[threadIdx.x >> 6] = s;
  __syncthreads();
  if (threadIdx.x == 0) {
    float tt = 0.0f;
#pragma unroll
    for (int q = 0; q < 16; ++q) tt += ws[q];
    out[0] = tt * invnP;
  }
}

// ---------------------------------------------------------------------------
extern "C" void kernel_launch(void* const* d_in, const int* in_sizes, int n_in,
                              void* d_out, int out_size, void* d_ws, size_t ws_size,
                              hipStream_t stream) {
  const float* x  = (const float*)d_in[0];
  const int*   ei = (const int*)d_in[1];
  const int*   ep = (const int*)d_in[2];
  const int*   en = (const int*)d_in[3];
  const float* W  = (const float*)d_in[4];
  float* out = (float*)d_out;

  int N  = in_sizes[0] / 128;   // 100000 nodes
  int nE = in_sizes[1] / 2;     // 1600000 edges
  int nP = in_sizes[2] / 2;     // 30000 pos (== neg)

  size_t zBytes   = (size_t)N * 256 * sizeof(float);
  size_t aggBytes = (size_t)N * 128 * sizeof(float);
  if (ws_size < zBytes + aggBytes) return;

  char* ws = (char*)d_ws;
  float* z   = (float*)ws;                 // written LAST (by gemm)
  float* agg = (float*)(ws + zBytes);

  // CSR temporaries overlaid inside the z region (dead before gemm)
  int* cnt        = (int*)ws;              // N
  int* offs       = cnt + N;               // N+1
  int* pos        = offs + N + 1;          // N
  int* bsum       = pos + N;               // <= 4096
  int* sorted_src = bsum + 4096;           // nE

  // per-block partials overlaid in the agg region (dead after gemm)
  float* partial = agg;

  int nb = (N + 255) / 256;

  hipMemsetAsync(cnt, 0, (size_t)N * sizeof(int), stream);

  const int* src = ei;
  const int* dst = ei + nE;

  int eb = (nE + 255) / 256;
  sge_count<<<eb, 256, 0, stream>>>(dst, cnt, nE);
  sge_blocksum<<<nb, 256, 0, stream>>>(cnt, bsum, N);
  sge_scan_top<<<1, 64, 0, stream>>>(bsum, offs, nb, N, nE);
  sge_scan_block<<<nb, 256, 0, stream>>>(cnt, bsum, offs, pos, N);
  sge_fill<<<eb, 256, 0, stream>>>(src, dst, pos, sorted_src, nE);
  sge_gather<<<(N + 3) / 4, 256, 0, stream>>>(x, sorted_src, offs, agg, N);

  sge_gemm<<<(N + 31) / 32, 256, 0, stream>>>(agg, W, z);

  int eblocks = (2 * nP + 3) / 4;
  sge_energy<<<eblocks, 256, 0, stream>>>(z, ep, en, partial, nP);
  sge_reduce<<<1, 1024, 0, stream>>>(partial, eblocks, 1.0f / (float)nP, out);
}

// Round 17
// 871.795 us; speedup vs baseline: 1.5066x; 1.5066x over previous
//
#include <hip/hip_runtime.h>
#include <hip/hip_bf16.h>

// ---------------------------------------------------------------------------
// Phase 1a: CSR build by dst, then gather-aggregate
// ---------------------------------------------------------------------------

__global__ __launch_bounds__(256) void sge_count(
    const int* __restrict__ dst, int* __restrict__ cnt, int nE) {
  int e = blockIdx.x * 256 + threadIdx.x;
  if (e >= nE) return;
  atomicAdd(&cnt[dst[e]], 1);
}

__global__ __launch_bounds__(256) void sge_blocksum(
    const int* __restrict__ cnt, int* __restrict__ bsum, int N) {
  int i = blockIdx.x * 256 + threadIdx.x;
  int v = (i < N) ? cnt[i] : 0;
#pragma unroll
  for (int o = 1; o < 64; o <<= 1) v += __shfl_xor(v, o);
  __shared__ int ws[4];
  int lane = threadIdx.x & 63, wid = threadIdx.x >> 6;
  if (lane == 0) ws[wid] = v;
  __syncthreads();
  if (threadIdx.x == 0)
    bsum[blockIdx.x] = ws[0] + ws[1] + ws[2] + ws[3];
}

__global__ __launch_bounds__(64) void sge_scan_top(
    int* __restrict__ bsum, int* __restrict__ offs, int nb, int N, int nE) {
  int lane = threadIdx.x;
  int carry = 0;
  for (int base = 0; base < nb; base += 64) {
    int i = base + lane;
    int v = (i < nb) ? bsum[i] : 0;
    int s = v;
#pragma unroll
    for (int o = 1; o < 64; o <<= 1) {
      int t = __shfl_up(s, o);
      if (lane >= o) s += t;
    }
    if (i < nb) bsum[i] = carry + s - v;  // exclusive
    carry += __shfl(s, 63);
  }
  if (lane == 0) offs[N] = nE;
}

__global__ __launch_bounds__(256) void sge_scan_block(
    const int* __restrict__ cnt, const int* __restrict__ bsum,
    int* __restrict__ offs, int* __restrict__ pos, int N) {
  int i = blockIdx.x * 256 + threadIdx.x;
  int v = (i < N) ? cnt[i] : 0;
  int lane = threadIdx.x & 63, wid = threadIdx.x >> 6;
  int s = v;
#pragma unroll
  for (int o = 1; o < 64; o <<= 1) {
    int t = __shfl_up(s, o);
    if (lane >= o) s += t;
  }
  __shared__ int ws[4];
  if (lane == 63) ws[wid] = s;
  __syncthreads();
  int wbase = 0;
  for (int w = 0; w < wid; ++w) wbase += ws[w];
  if (i < N) {
    int o = bsum[blockIdx.x] + wbase + s - v;
    offs[i] = o;
    pos[i] = o;
  }
}

__global__ __launch_bounds__(256) void sge_fill(
    const int* __restrict__ src, const int* __restrict__ dst,
    int* __restrict__ pos, int* __restrict__ sorted_src, int nE) {
  int e = blockIdx.x * 256 + threadIdx.x;
  if (e >= nE) return;
  int p = atomicAdd(&pos[dst[e]], 1);
  sorted_src[p] = src[e];
}

// 64 lanes per node, two 32-lane halves split the edge range
__global__ __launch_bounds__(256) void sge_gather(
    const float* __restrict__ x, const int* __restrict__ sorted_src,
    const int* __restrict__ offs, float* __restrict__ agg, int N) {
  int node = blockIdx.x * 4 + (threadIdx.x >> 6);
  int lane = threadIdx.x & 63;
  int h = lane >> 5;           // half 0/1
  int c4 = (lane & 31) << 2;   // float4 column offset
  if (node >= N) return;
  int e0 = offs[node], e1 = offs[node + 1];
  float4 A = {0.f, 0.f, 0.f, 0.f}, B = {0.f, 0.f, 0.f, 0.f};
  int e = e0 + h;              // this half's edges: e0+h, e0+h+2, ...
  for (; e + 2 < e1; e += 4) {
    int s0 = sorted_src[e];
    int s1 = sorted_src[e + 2];
    float4 v0 = *(const float4*)&x[(size_t)s0 * 128 + c4];
    float4 v1 = *(const float4*)&x[(size_t)s1 * 128 + c4];
    A.x += v0.x; A.y += v0.y; A.z += v0.z; A.w += v0.w;
    B.x += v1.x; B.y += v1.y; B.z += v1.z; B.w += v1.w;
  }
  if (e < e1) {
    float4 v0 = *(const float4*)&x[(size_t)sorted_src[e] * 128 + c4];
    A.x += v0.x; A.y += v0.y; A.z += v0.z; A.w += v0.w;
  }
  float4 S;
  S.x = A.x + B.x; S.y = A.y + B.y; S.z = A.z + B.z; S.w = A.w + B.w;
  S.x += __shfl_xor(S.x, 32);
  S.y += __shfl_xor(S.y, 32);
  S.z += __shfl_xor(S.z, 32);
  S.w += __shfl_xor(S.w, 32);
  if (h == 0) {
    float inv = 1.0f / fmaxf((float)(e1 - e0), 1.0f);
    float4 r;
    r.x = S.x * inv; r.y = S.y * inv; r.z = S.z * inv; r.w = S.w * inv;
    *(float4*)&agg[(size_t)node * 128 + c4] = r;
  }
}

// ---------------------------------------------------------------------------
// Phase 1b: z = agg @ W   [N,128]@[128,256] -> [N,256]
// ---------------------------------------------------------------------------
__global__ __launch_bounds__(256) void sge_gemm(
    const float* __restrict__ agg, const float* __restrict__ W,
    float* __restrict__ z) {
  __shared__ float xs[32][128];
  int n0 = blockIdx.x * 32;
  int t = threadIdx.x;
#pragma unroll
  for (int i = 0; i < 16; ++i) {
    int idx = t + i * 256;
    int r = idx >> 7;
    int c = idx & 127;
    xs[r][c] = agg[(long long)(n0 + r) * 128 + c];
  }
  __syncthreads();
  int wv = t >> 6, lane = t & 63;
  int r0 = wv * 8;
  float acc[8][4];
#pragma unroll
  for (int r = 0; r < 8; ++r)
#pragma unroll
    for (int q = 0; q < 4; ++q) acc[r][q] = 0.f;
  for (int k = 0; k < 128; k += 4) {
    float4 xv[8];
#pragma unroll
    for (int r = 0; r < 8; ++r) xv[r] = *(const float4*)&xs[r0 + r][k];
#pragma unroll
    for (int kk = 0; kk < 4; ++kk) {
      const float* Wr = W + (k + kk) * 256 + lane;
      float w0 = Wr[0], w1 = Wr[64], w2 = Wr[128], w3 = Wr[192];
#pragma unroll
      for (int r = 0; r < 8; ++r) {
        float xk = (kk == 0) ? xv[r].x
                 : (kk == 1) ? xv[r].y
                 : (kk == 2) ? xv[r].z : xv[r].w;
        acc[r][0] = fmaf(xk, w0, acc[r][0]);
        acc[r][1] = fmaf(xk, w1, acc[r][1]);
        acc[r][2] = fmaf(xk, w2, acc[r][2]);
        acc[r][3] = fmaf(xk, w3, acc[r][3]);
      }
    }
  }
#pragma unroll
  for (int r = 0; r < 8; ++r) {
    float* zr = z + (long long)(n0 + r0 + r) * 256 + lane;
#pragma unroll
    for (int q = 0; q < 4; ++q) zr[q * 64] = acc[r][q];
  }
}

// ---------------------------------------------------------------------------
// Phase 2 (v18): v14's 2-waves-per-pair shape, but each LANE runs two
// half-width chains (16 cols each) -> 2x ILP at the SAME total V state
// (V[16]+V[16] = 32 regs, exactly v14's V[32]; v17 spilled because it
// doubled to 64). Lane = (row = l>>1, colhalf = l&1); rows duplicated x2
// so lanes 2r/2r+1 stay bit-identical (partner sum via DPP quad_perm).
//   wave0: chain A = xy->fab (reads E of gba), chain B = yx->gba (reads fab)
//   wave1: chain A = xx->faa (self),           chain B = yy->gbb (self)
// Final-eps refresh via exp2(1.5625*log2(V)) (v11-validated).
// ---------------------------------------------------------------------------
template <int CTRL>
__device__ __forceinline__ float dpp_max(float x) {
  int r = __builtin_amdgcn_update_dpp(__float_as_int(x), __float_as_int(x),
                                      CTRL, 0xF, 0xF, false);
  return fmaxf(x, __int_as_float(r));
}
template <int CTRL>
__device__ __forceinline__ float dpp_add(float x) {
  int r = __builtin_amdgcn_update_dpp(0, __float_as_int(x), CTRL, 0xF, 0xF, true);
  return x + __int_as_float(r);
}
__device__ __forceinline__ float rdlane(float v, int lane) {
  return __int_as_float(__builtin_amdgcn_readlane(__float_as_int(v), lane));
}

__global__ __launch_bounds__(256, 4) void sge_energy(
    const float* __restrict__ z, const int* __restrict__ ep,
    const int* __restrict__ en, float* __restrict__ partial, int nP) {
  __shared__ __align__(16) float EbA[4][32];   // chain-A E per wave
  __shared__ __align__(16) float EbB[4][32];   // chain-B E per wave
  __shared__ __align__(16) float Nbuf[4][64];  // nx[32] | ny[32] per wave
  __shared__ float red[2][2];

  int t = threadIdx.x;
  int wv = t >> 6;        // wave 0..3
  int pl = wv >> 1;       // pair slot 0/1
  int w = wv & 1;         // 0: {xy,yx}   1: {xx,yy}
  int l = t & 63;
  int row = l >> 1;       // 0..31
  int ch = l & 1;         // column half: cols [16*ch, 16*ch+16)

  int pair = blockIdx.x * 2 + pl;
  bool isPos = pair < nP;
  int idx = isPos ? pair : pair - nP;
  const int* E = isPos ? ep : en;
  int na = E[idx], nb = E[idx + nP];

  const float* zx = z + (size_t)na * 256;
  const float* zy = z + (size_t)nb * 256;

  // chain A row = x[row], chain B row = y[row] (both waves)
  float xrow[8], yrow[8];
  {
    float4 a0 = ((const float4*)(zx + row * 8))[0];
    float4 a1 = ((const float4*)(zx + row * 8))[1];
    float4 b0 = ((const float4*)(zy + row * 8))[0];
    float4 b1 = ((const float4*)(zy + row * 8))[1];
    xrow[0] = a0.x; xrow[1] = a0.y; xrow[2] = a0.z; xrow[3] = a0.w;
    xrow[4] = a1.x; xrow[5] = a1.y; xrow[6] = a1.z; xrow[7] = a1.w;
    yrow[0] = b0.x; yrow[1] = b0.y; yrow[2] = b0.z; yrow[3] = b0.w;
    yrow[4] = b1.x; yrow[5] = b1.y; yrow[6] = b1.z; yrow[7] = b1.w;
  }
  float nxr = xrow[0] * xrow[0];
  float nyr = yrow[0] * yrow[0];
#pragma unroll
  for (int d = 1; d < 8; ++d) {
    nxr = fmaf(xrow[d], xrow[d], nxr);
    nyr = fmaf(yrow[d], yrow[d], nyr);
  }
  // lanes 2r and 2r+1 write identical values to identical slots (benign)
  Nbuf[wv][row] = nxr;
  Nbuf[wv][32 + row] = nyr;
  __builtin_amdgcn_wave_barrier();

  // column sources per chain (rows fixed: A=x, B=y)
  const float4* colsA = (const float4*)((w == 0) ? zy : zx);
  const float4* colsB = (const float4*)((w == 0) ? zx : zy);
  const float* NcA = (w == 0) ? (Nbuf[wv] + 32) : Nbuf[wv];
  const float* NcB = (w == 0) ? Nbuf[wv] : (Nbuf[wv] + 32);

  const float RLNE = 1.44269504088896340736f;  // log2(e)
  const float LN2 = 0.69314718055994530942f;
  const float LN32 = 3.46573590279972654709f;  // ln(32)
  const float K20 = RLNE / 10.0f;

  // build VA[16] (chain A) and VB[16] (chain B); norm-form distance
  float VA[16], VB[16];
#pragma unroll
  for (int jq = 0; jq < 4; ++jq) {
    float4 nA4 = ((const float4*)(NcA + ch * 16))[jq];
    float4 nB4 = ((const float4*)(NcB + ch * 16))[jq];
#pragma unroll
    for (int k = 0; k < 4; ++k) {
      int jj = jq * 4 + k;
      int j = ch * 16 + jj;
      float4 a0 = colsA[2 * j];
      float4 a1 = colsA[2 * j + 1];
      float4 b0 = colsB[2 * j];
      float4 b1 = colsB[2 * j + 1];
      float dA = xrow[0] * a0.x;
      float dB = yrow[0] * b0.x;
      dA = fmaf(xrow[1], a0.y, dA); dB = fmaf(yrow[1], b0.y, dB);
      dA = fmaf(xrow[2], a0.z, dA); dB = fmaf(yrow[2], b0.z, dB);
      dA = fmaf(xrow[3], a0.w, dA); dB = fmaf(yrow[3], b0.w, dB);
      dA = fmaf(xrow[4], a1.x, dA); dB = fmaf(yrow[4], b1.x, dB);
      dA = fmaf(xrow[5], a1.y, dA); dB = fmaf(yrow[5], b1.y, dB);
      dA = fmaf(xrow[6], a1.z, dA); dB = fmaf(yrow[6], b1.z, dB);
      dA = fmaf(xrow[7], a1.w, dA); dB = fmaf(yrow[7], b1.w, dB);
      float nA = (k == 0) ? nA4.x : (k == 1) ? nA4.y : (k == 2) ? nA4.z : nA4.w;
      float nB = (k == 0) ? nB4.x : (k == 1) ? nB4.y : (k == 2) ? nB4.z : nB4.w;
      float sqA = fmaf(-2.0f, dA, nxr + nA);
      float sqB = fmaf(-2.0f, dB, nyr + nB);
      float CA = __builtin_amdgcn_sqrtf(fmaxf(sqA, 0.0f) + 1e-8f);
      float CB = __builtin_amdgcn_sqrtf(fmaxf(sqB, 0.0f) + 1e-8f);
      VA[jj] = __builtin_amdgcn_exp2f(-CA * K20);
      VB[jj] = __builtin_amdgcn_exp2f(-CB * K20);
    }
  }

  float* EAw = EbA[wv];
  float* EBw = EbB[wv];
  const float* ErdA = (w == 0) ? EBw : EAw;  // E consumed by chain A
  const float* ErdB = (w == 0) ? EAw : EBw;  // E consumed by chain B

  float PA = 0.0f, PB = 0.0f;
  float epsv = 10.0f;

#pragma unroll 1
  for (int it = 0; it < 9; ++it) {
    float eps = (it == 8) ? 0.05f : epsv;
    float k2 = RLNE / eps;
    float eln2 = eps * LN2;
    float c32 = eps * LN32;

    if (it == 8) {
      // eps 0.078125 -> 0.05: exponent scales by 1.5625 (v11-validated)
#pragma unroll
      for (int j = 0; j < 16; ++j) {
        VA[j] = __builtin_amdgcn_exp2f(1.5625f * __builtin_amdgcn_logf(VA[j]));
        VB[j] = __builtin_amdgcn_exp2f(1.5625f * __builtin_amdgcn_logf(VB[j]));
      }
    } else if (it > 0) {
#pragma unroll
      for (int j = 0; j < 16; ++j) {
        VA[j] *= VA[j];
        VB[j] *= VB[j];
      }
    }

    float mA, mB;
    if (it >= 7) {
      float a = PA, b = PB;
      a = dpp_max<0x111>(a); b = dpp_max<0x111>(b);
      a = dpp_max<0x112>(a); b = dpp_max<0x112>(b);
      a = dpp_max<0x114>(a); b = dpp_max<0x114>(b);
      a = dpp_max<0x118>(a); b = dpp_max<0x118>(b);
      a = dpp_max<0x142>(a); b = dpp_max<0x142>(b);
      mA = fmaxf(rdlane(a, 31), rdlane(a, 63));
      mB = fmaxf(rdlane(b, 31), rdlane(b, 63));
    } else {
      mA = 0.0f;
      mB = 0.0f;
    }

    // lanes 2r/2r+1 write the same value to the same slot (benign)
    EAw[row] = __builtin_amdgcn_exp2f((PA - mA) * k2);
    EBw[row] = __builtin_amdgcn_exp2f((PB - mB) * k2);
    __builtin_amdgcn_wave_barrier();

    float sA0 = 0.f, sA1 = 0.f, sA2 = 0.f, sA3 = 0.f;
    float sB0 = 0.f, sB1 = 0.f, sB2 = 0.f, sB3 = 0.f;
#pragma unroll
    for (int jq = 0; jq < 4; ++jq) {
      float4 EvA = ((const float4*)(ErdA + ch * 16))[jq];
      float4 EvB = ((const float4*)(ErdB + ch * 16))[jq];
      sA0 = fmaf(EvA.x, VA[4 * jq + 0], sA0);
      sB0 = fmaf(EvB.x, VB[4 * jq + 0], sB0);
      sA1 = fmaf(EvA.y, VA[4 * jq + 1], sA1);
      sB1 = fmaf(EvB.y, VB[4 * jq + 1], sB1);
      sA2 = fmaf(EvA.z, VA[4 * jq + 2], sA2);
      sB2 = fmaf(EvB.z, VB[4 * jq + 2], sB2);
      sA3 = fmaf(EvA.w, VA[4 * jq + 3], sA3);
      sB3 = fmaf(EvB.w, VB[4 * jq + 3], sB3);
    }
    float sA = (sA0 + sA1) + (sA2 + sA3);
    float sB = (sB0 + sB1) + (sB2 + sB3);
    sA = dpp_add<0xB1>(sA);   // + partner lane (l^1): other column half
    sB = dpp_add<0xB1>(sB);
    sA = fmaxf(sA, 1e-37f);
    sB = fmaxf(sB, 1e-37f);
    __builtin_amdgcn_wave_barrier();  // reads done before next iter's writes

    float mUA = (w == 0) ? mB : mA;   // max used in chain A's LSE
    float mUB = (w == 0) ? mA : mB;
    PA = 0.5f * (PA + (c32 - mUA - eln2 * __builtin_amdgcn_logf(sA)));
    PB = 0.5f * (PB + (c32 - mUB - eln2 * __builtin_amdgcn_logf(sB)));
    epsv *= 0.5f;
  }

  // wave sum of PA+PB (each row counted twice -> /64 later)
  float d = PA + PB;
  d = dpp_add<0x111>(d);
  d = dpp_add<0x112>(d);
  d = dpp_add<0x114>(d);
  d = dpp_add<0x118>(d);
  d = dpp_add<0x142>(d);
  float sum = rdlane(d, 31) + rdlane(d, 63);
  if (l == 0) red[pl][w] = sum;
  __syncthreads();
  if (t == 0) {
    float tot = 0.0f;
#pragma unroll
    for (int q = 0; q < 2; ++q) {
      int pr = blockIdx.x * 2 + q;
      float e = (red[q][0] - red[q][1]) * (1.0f / 64.0f);
      float term;
      if (pr < nP) {
        term = e * e;
      } else {
        float mm = fmaxf(1.0f - e, 0.0f);
        term = mm * mm;
      }
      tot += term;
    }
    partial[blockIdx.x] = tot;   // no atomics: per-block partial
  }
}

// single-block final reduction: out = sum(partial) / nP
__global__ __launch_bounds__(1024) void sge_reduce(
    const float* __restrict__ partial, int n, float invnP,
    float* __restrict__ out) {
  __shared__ float ws[16];
  float s = 0.0f;
  for (int i = threadIdx.x; i < n; i += 1024) s += partial[i];
#pragma unroll
  for (int o = 1; o < 64; o <<= 1) s += __shfl_xor(s, o);
  if ((threadIdx.x & 63) == 0) ws[threadIdx.x >> 6] = s;
  __syncthreads();
  if (threadIdx.x == 0) {
    float tt = 0.0f;
#pragma unroll
    for (int q = 0; q < 16; ++q) tt += ws[q];
    out[0] = tt * invnP;
  }
}

// ---------------------------------------------------------------------------
extern "C" void kernel_launch(void* const* d_in, const int* in_sizes, int n_in,
                              void* d_out, int out_size, void* d_ws, size_t ws_size,
                              hipStream_t stream) {
  const float* x  = (const float*)d_in[0];
  const int*   ei = (const int*)d_in[1];
  const int*   ep = (const int*)d_in[2];
  const int*   en = (const int*)d_in[3];
  const float* W  = (const float*)d_in[4];
  float* out = (float*)d_out;

  int N  = in_sizes[0] / 128;   // 100000 nodes
  int nE = in_sizes[1] / 2;     // 1600000 edges
  int nP = in_sizes[2] / 2;     // 30000 pos (== neg)

  size_t zBytes   = (size_t)N * 256 * sizeof(float);
  size_t aggBytes = (size_t)N * 128 * sizeof(float);
  if (ws_size < zBytes + aggBytes) return;

  char* ws = (char*)d_ws;
  float* z   = (float*)ws;                 // written LAST (by gemm)
  float* agg = (float*)(ws + zBytes);

  // CSR temporaries overlaid inside the z region (dead before gemm)
  int* cnt        = (int*)ws;              // N
  int* offs       = cnt + N;               // N+1
  int* pos        = offs + N + 1;          // N
  int* bsum       = pos + N;               // <= 4096
  int* sorted_src = bsum + 4096;           // nE

  // per-block partials overlaid in the agg region (dead after gemm)
  float* partial = agg;

  int nb = (N + 255) / 256;

  hipMemsetAsync(cnt, 0, (size_t)N * sizeof(int), stream);

  const int* src = ei;
  const int* dst = ei + nE;

  int eb = (nE + 255) / 256;
  sge_count<<<eb, 256, 0, stream>>>(dst, cnt, nE);
  sge_blocksum<<<nb, 256, 0, stream>>>(cnt, bsum, N);
  sge_scan_top<<<1, 64, 0, stream>>>(bsum, offs, nb, N, nE);
  sge_scan_block<<<nb, 256, 0, stream>>>(cnt, bsum, offs, pos, N);
  sge_fill<<<eb, 256, 0, stream>>>(src, dst, pos, sorted_src, nE);
  sge_gather<<<(N + 3) / 4, 256, 0, stream>>>(x, sorted_src, offs, agg, N);

  sge_gemm<<<(N + 31) / 32, 256, 0, stream>>>(agg, W, z);

  int eblocks = nP;  // 2 pairs per block, 2*nP pairs total
  sge_energy<<<eblocks, 256, 0, stream>>>(z, ep, en, partial, nP);
  sge_reduce<<<1, 1024, 0, stream>>>(partial, eblocks, 1.0f / (float)nP, out);
}

// Round 19
// 641.420 us; speedup vs baseline: 2.0477x; 1.3592x over previous
//
#include <hip/hip_runtime.h>
#include <hip/hip_bf16.h>

// ---------------------------------------------------------------------------
// Phase 1a: CSR build by dst
// ---------------------------------------------------------------------------

__global__ __launch_bounds__(256) void sge_count(
    const int* __restrict__ dst, int* __restrict__ cnt, int nE) {
  int e = blockIdx.x * 256 + threadIdx.x;
  if (e >= nE) return;
  atomicAdd(&cnt[dst[e]], 1);
}

__global__ __launch_bounds__(256) void sge_blocksum(
    const int* __restrict__ cnt, int* __restrict__ bsum, int N) {
  int i = blockIdx.x * 256 + threadIdx.x;
  int v = (i < N) ? cnt[i] : 0;
#pragma unroll
  for (int o = 1; o < 64; o <<= 1) v += __shfl_xor(v, o);
  __shared__ int ws[4];
  int lane = threadIdx.x & 63, wid = threadIdx.x >> 6;
  if (lane == 0) ws[wid] = v;
  __syncthreads();
  if (threadIdx.x == 0)
    bsum[blockIdx.x] = ws[0] + ws[1] + ws[2] + ws[3];
}

__global__ __launch_bounds__(64) void sge_scan_top(
    int* __restrict__ bsum, int* __restrict__ offs, int nb, int N, int nE) {
  int lane = threadIdx.x;
  int carry = 0;
  for (int base = 0; base < nb; base += 64) {
    int i = base + lane;
    int v = (i < nb) ? bsum[i] : 0;
    int s = v;
#pragma unroll
    for (int o = 1; o < 64; o <<= 1) {
      int t = __shfl_up(s, o);
      if (lane >= o) s += t;
    }
    if (i < nb) bsum[i] = carry + s - v;  // exclusive
    carry += __shfl(s, 63);
  }
  if (lane == 0) offs[N] = nE;
}

__global__ __launch_bounds__(256) void sge_scan_block(
    const int* __restrict__ cnt, const int* __restrict__ bsum,
    int* __restrict__ offs, int* __restrict__ pos, int N) {
  int i = blockIdx.x * 256 + threadIdx.x;
  int v = (i < N) ? cnt[i] : 0;
  int lane = threadIdx.x & 63, wid = threadIdx.x >> 6;
  int s = v;
#pragma unroll
  for (int o = 1; o < 64; o <<= 1) {
    int t = __shfl_up(s, o);
    if (lane >= o) s += t;
  }
  __shared__ int ws[4];
  if (lane == 63) ws[wid] = s;
  __syncthreads();
  int wbase = 0;
  for (int w = 0; w < wid; ++w) wbase += ws[w];
  if (i < N) {
    int o = bsum[blockIdx.x] + wbase + s - v;
    offs[i] = o;
    pos[i] = o;
  }
}

__global__ __launch_bounds__(256) void sge_fill(
    const int* __restrict__ src, const int* __restrict__ dst,
    int* __restrict__ pos, int* __restrict__ sorted_src, int nE) {
  int e = blockIdx.x * 256 + threadIdx.x;
  if (e >= nE) return;
  int p = atomicAdd(&pos[dst[e]], 1);
  sorted_src[p] = src[e];
}

// ---------------------------------------------------------------------------
// Phase 1b (fused): gather-aggregate INTO the LDS tile, then z = xs @ W.
// Block = 32 nodes. Gather: 8 threads/node x 16 cols, CSR loop, 4 float4
// accumulators; deg-normalize; write xs[r][c0..c0+15]. Then unchanged GEMM.
// NOTE: CSR arrays live AFTER the z region (R18 crash: they overlapped z).
// ---------------------------------------------------------------------------
__global__ __launch_bounds__(256) void sge_gemm(
    const float* __restrict__ x, const int* __restrict__ sorted_src,
    const int* __restrict__ offs, const float* __restrict__ W,
    float* __restrict__ z) {
  __shared__ float xs[32][128];
  int n0 = blockIdx.x * 32;
  int t = threadIdx.x;

  {
    int r = t >> 3;          // node slot 0..31
    int c0 = (t & 7) << 4;   // 16-column span
    int node = n0 + r;       // N % 32 == 0: always valid
    int e0 = offs[node], e1 = offs[node + 1];
    float4 a0 = {0.f, 0.f, 0.f, 0.f}, a1 = {0.f, 0.f, 0.f, 0.f};
    float4 a2 = {0.f, 0.f, 0.f, 0.f}, a3 = {0.f, 0.f, 0.f, 0.f};
    for (int e = e0; e < e1; ++e) {
      int s = sorted_src[e];  // uniform across the 8 threads of this node
      const float4* xr = (const float4*)&x[(size_t)s * 128 + c0];
      float4 v0 = xr[0], v1 = xr[1], v2 = xr[2], v3 = xr[3];
      a0.x += v0.x; a0.y += v0.y; a0.z += v0.z; a0.w += v0.w;
      a1.x += v1.x; a1.y += v1.y; a1.z += v1.z; a1.w += v1.w;
      a2.x += v2.x; a2.y += v2.y; a2.z += v2.z; a2.w += v2.w;
      a3.x += v3.x; a3.y += v3.y; a3.z += v3.z; a3.w += v3.w;
    }
    float inv = 1.0f / fmaxf((float)(e1 - e0), 1.0f);
    float4* xw = (float4*)&xs[r][c0];
    float4 w0, w1, w2, w3;
    w0.x = a0.x * inv; w0.y = a0.y * inv; w0.z = a0.z * inv; w0.w = a0.w * inv;
    w1.x = a1.x * inv; w1.y = a1.y * inv; w1.z = a1.z * inv; w1.w = a1.w * inv;
    w2.x = a2.x * inv; w2.y = a2.y * inv; w2.z = a2.z * inv; w2.w = a2.w * inv;
    w3.x = a3.x * inv; w3.y = a3.y * inv; w3.z = a3.z * inv; w3.w = a3.w * inv;
    xw[0] = w0; xw[1] = w1; xw[2] = w2; xw[3] = w3;
  }
  __syncthreads();

  int wv = t >> 6, lane = t & 63;
  int r0 = wv * 8;
  float acc[8][4];
#pragma unroll
  for (int r = 0; r < 8; ++r)
#pragma unroll
    for (int q = 0; q < 4; ++q) acc[r][q] = 0.f;
  for (int k = 0; k < 128; k += 4) {
    float4 xv[8];
#pragma unroll
    for (int r = 0; r < 8; ++r) xv[r] = *(const float4*)&xs[r0 + r][k];
#pragma unroll
    for (int kk = 0; kk < 4; ++kk) {
      const float* Wr = W + (k + kk) * 256 + lane;
      float w0 = Wr[0], w1 = Wr[64], w2 = Wr[128], w3 = Wr[192];
#pragma unroll
      for (int r = 0; r < 8; ++r) {
        float xk = (kk == 0) ? xv[r].x
                 : (kk == 1) ? xv[r].y
                 : (kk == 2) ? xv[r].z : xv[r].w;
        acc[r][0] = fmaf(xk, w0, acc[r][0]);
        acc[r][1] = fmaf(xk, w1, acc[r][1]);
        acc[r][2] = fmaf(xk, w2, acc[r][2]);
        acc[r][3] = fmaf(xk, w3, acc[r][3]);
      }
    }
  }
#pragma unroll
  for (int r = 0; r < 8; ++r) {
    float* zr = z + (long long)(n0 + r0 + r) * 256 + lane;
#pragma unroll
    for (int q = 0; q < 4; ++q) zr[q * 64] = acc[r][q];
  }
}

// ---------------------------------------------------------------------------
// Phase 2 (v14, verified twice): norm-form build via per-wave LDS norm
// exchange, global-direct column reads, C kept for the final-eps fresh-exp
// refresh, max-skip for iters 0..6, per-block partials (no atomics).
// ---------------------------------------------------------------------------
template <int CTRL>
__device__ __forceinline__ float dpp_max(float x) {
  int r = __builtin_amdgcn_update_dpp(__float_as_int(x), __float_as_int(x),
                                      CTRL, 0xF, 0xF, false);
  return fmaxf(x, __int_as_float(r));
}
template <int CTRL>
__device__ __forceinline__ float dpp_add(float x) {
  int r = __builtin_amdgcn_update_dpp(0, __float_as_int(x), CTRL, 0xF, 0xF, true);
  return x + __int_as_float(r);
}

__global__ __launch_bounds__(256, 4) void sge_energy(
    const float* __restrict__ z, const int* __restrict__ ep,
    const int* __restrict__ en, float* __restrict__ partial, int nP) {
  __shared__ __align__(16) float Ebuf[2][2][64];  // [pair][wave][64]
  __shared__ __align__(16) float Nbuf[2][2][64];  // [pair][wave][64] norms
  __shared__ float red[2][2];

  int t = threadIdx.x;
  int pl = t >> 7;        // pair-local index 0/1
  int tp = t & 127;       // thread within pair
  int w = tp >> 6;        // wave-in-pair: 0={xy,yx}, 1={xx,yy}
  int l = tp & 63;
  int row = l & 31;
  int own = l & 32;       // 0 = x-rows half, 32 = y-rows half

  int pair = blockIdx.x * 2 + pl;
  bool isPos = pair < nP;
  int idx = isPos ? pair : pair - nP;
  const int* E = isPos ? ep : en;
  int na = E[idx], nb = E[idx + nP];

  // own row straight from global
  const float* zrow = z + (size_t)(own ? nb : na) * 256 + row * 8;
  float4 r0 = ((const float4*)zrow)[0];
  float4 r1 = ((const float4*)zrow)[1];
  float xr[8];
  xr[0] = r0.x; xr[1] = r0.y; xr[2] = r0.z; xr[3] = r0.w;
  xr[4] = r1.x; xr[5] = r1.y; xr[6] = r1.z; xr[7] = r1.w;

  // own squared norm -> LDS exchange (same rb addressing as Ebuf)
  float nself = xr[0] * xr[0];
  nself = fmaf(xr[1], xr[1], nself); nself = fmaf(xr[2], xr[2], nself);
  nself = fmaf(xr[3], xr[3], nself); nself = fmaf(xr[4], xr[4], nself);
  nself = fmaf(xr[5], xr[5], nself); nself = fmaf(xr[6], xr[6], nself);
  nself = fmaf(xr[7], xr[7], nself);
  Nbuf[pl][w][l] = nself;
  __builtin_amdgcn_wave_barrier();

  bool colIsX = (w == 0) ? (own != 0) : (own == 0);
  const float4* zc = (const float4*)(z + (size_t)(colIsX ? na : nb) * 256);
  int rb = (w == 0) ? (own ^ 32) : own;
  const float* Nw = Nbuf[pl][w] + rb;

  const float RLNE = 1.44269504088896340736f;  // log2(e)
  const float LN2 = 0.69314718055994530942f;
  const float LN32 = 3.46573590279972654709f;  // ln(32)
  const float K20 = RLNE / 10.0f;
  const float NK28 = -RLNE / 0.05f;            // -k2 at final eps

  // build C (kept) and V = 2^(-C*k2_0); norm-form distance
  float C[32], V[32];
#pragma unroll
  for (int jq = 0; jq < 8; ++jq) {
    float4 nj4 = ((const float4*)Nw)[jq];
    float4 a[8];
#pragma unroll
    for (int k = 0; k < 4; ++k) {
      a[2 * k] = zc[8 * jq + 2 * k];
      a[2 * k + 1] = zc[8 * jq + 2 * k + 1];
    }
#pragma unroll
    for (int k = 0; k < 4; ++k) {
      int j = jq * 4 + k;
      float4 a0 = a[2 * k], a1 = a[2 * k + 1];
      float d = xr[0] * a0.x;
      d = fmaf(xr[1], a0.y, d); d = fmaf(xr[2], a0.z, d);
      d = fmaf(xr[3], a0.w, d); d = fmaf(xr[4], a1.x, d);
      d = fmaf(xr[5], a1.y, d); d = fmaf(xr[6], a1.z, d);
      d = fmaf(xr[7], a1.w, d);
      float nj = (k == 0) ? nj4.x : (k == 1) ? nj4.y : (k == 2) ? nj4.z : nj4.w;
      float sq = fmaf(-2.0f, d, nself + nj);
      float Cv = __builtin_amdgcn_sqrtf(fmaxf(sq, 0.0f) + 1e-8f);
      C[j] = Cv;
      V[j] = __builtin_amdgcn_exp2f(-Cv * K20);
    }
  }

  float* Ew = Ebuf[pl][w];

  float P = 0.0f;
  float epsv = 10.0f;

#pragma unroll 1
  for (int it = 0; it < 9; ++it) {
    float eps = (it == 8) ? 0.05f : epsv;
    float k2 = RLNE / eps;
    float eln2 = eps * LN2;
    float c32 = eps * LN32;

    if (it == 8) {
#pragma unroll
      for (int j = 0; j < 32; ++j)
        V[j] = __builtin_amdgcn_exp2f(C[j] * NK28);
    } else if (it > 0) {
#pragma unroll
      for (int j = 0; j < 32; ++j) V[j] *= V[j];
    }

    float mOwn, mRead;
    if (it >= 7) {
      float m = P;
      m = dpp_max<0x111>(m);
      m = dpp_max<0x112>(m);
      m = dpp_max<0x114>(m);
      m = dpp_max<0x118>(m);
      m = dpp_max<0x142>(m);  // lanes 31/63 hold half maxes
      float g0 = __int_as_float(__builtin_amdgcn_readlane(__float_as_int(m), 31));
      float g1 = __int_as_float(__builtin_amdgcn_readlane(__float_as_int(m), 63));
      mOwn = own ? g1 : g0;
      mRead = (w == 0) ? (own ? g0 : g1) : mOwn;
    } else {
      mOwn = 0.0f;
      mRead = 0.0f;
    }

    Ew[l] = __builtin_amdgcn_exp2f((P - mOwn) * k2);
    __builtin_amdgcn_wave_barrier();

    float s0 = 0.f, s1 = 0.f, s2 = 0.f, s3 = 0.f;
#pragma unroll
    for (int jq = 0; jq < 8; ++jq) {
      float4 Ev = ((const float4*)(Ew + rb))[jq];
      s0 = fmaf(Ev.x, V[4 * jq + 0], s0);
      s1 = fmaf(Ev.y, V[4 * jq + 1], s1);
      s2 = fmaf(Ev.z, V[4 * jq + 2], s2);
      s3 = fmaf(Ev.w, V[4 * jq + 3], s3);
    }
    float s = fmaxf((s0 + s1) + (s2 + s3), 1e-37f);
    __builtin_amdgcn_wave_barrier();  // reads complete before next write

    P = 0.5f * (P + (c32 - mRead - eln2 * __builtin_amdgcn_logf(s)));
    epsv *= 0.5f;
  }

  // wave sums via DPP
  float d = P;
  d = dpp_add<0x111>(d);
  d = dpp_add<0x112>(d);
  d = dpp_add<0x114>(d);
  d = dpp_add<0x118>(d);
  d = dpp_add<0x142>(d);
  float s31 = __int_as_float(__builtin_amdgcn_readlane(__float_as_int(d), 31));
  float s63 = __int_as_float(__builtin_amdgcn_readlane(__float_as_int(d), 63));
  if (l == 0) red[pl][w] = s31 + s63;
  __syncthreads();
  if (t == 0) {
    float tot = 0.0f;
#pragma unroll
    for (int q = 0; q < 2; ++q) {
      int pr = blockIdx.x * 2 + q;
      float e = (red[q][0] - red[q][1]) * (1.0f / 32.0f);
      float term;
      if (pr < nP) {
        term = e * e;
      } else {
        float mm = fmaxf(1.0f - e, 0.0f);
        term = mm * mm;
      }
      tot += term;
    }
    partial[blockIdx.x] = tot;   // no atomics: per-block partial
  }
}

// single-block final reduction: out = sum(partial) / nP
__global__ __launch_bounds__(1024) void sge_reduce(
    const float* __restrict__ partial, int n, float invnP,
    float* __restrict__ out) {
  __shared__ float ws[16];
  float s = 0.0f;
  for (int i = threadIdx.x; i < n; i += 1024) s += partial[i];
#pragma unroll
  for (int o = 1; o < 64; o <<= 1) s += __shfl_xor(s, o);
  if ((threadIdx.x & 63) == 0) ws[threadIdx.x >> 6] = s;
  __syncthreads();
  if (threadIdx.x == 0) {
    float tt = 0.0f;
#pragma unroll
    for (int q = 0; q < 16; ++q) tt += ws[q];
    out[0] = tt * invnP;
  }
}

// ---------------------------------------------------------------------------
extern "C" void kernel_launch(void* const* d_in, const int* in_sizes, int n_in,
                              void* d_out, int out_size, void* d_ws, size_t ws_size,
                              hipStream_t stream) {
  const float* x  = (const float*)d_in[0];
  const int*   ei = (const int*)d_in[1];
  const int*   ep = (const int*)d_in[2];
  const int*   en = (const int*)d_in[3];
  const float* W  = (const float*)d_in[4];
  float* out = (float*)d_out;

  int N  = in_sizes[0] / 128;   // 100000 nodes
  int nE = in_sizes[1] / 2;     // 1600000 edges
  int nP = in_sizes[2] / 2;     // 30000 pos (== neg)

  size_t zBytes   = (size_t)N * 256 * sizeof(float);
  size_t aggBytes = (size_t)N * 128 * sizeof(float);
  if (ws_size < zBytes + aggBytes) return;

  char* ws = (char*)d_ws;
  float* z = (float*)ws;  // [0, zBytes): written by gemm, read by energy

  // CSR temporaries + partials AFTER the z region (fused gemm reads CSR
  // while writing z — they must not overlap; R18's crash was this overlay)
  int* base2      = (int*)(ws + zBytes);
  int* cnt        = base2;                 // N
  int* offs       = cnt + N;               // N+1
  int* pos        = offs + N + 1;          // N
  int* bsum       = pos + N;               // <= 4096
  int* sorted_src = bsum + 4096;           // nE
  float* partial  = (float*)(sorted_src + nE);  // nP floats
  // total: ~1.93M ints + 30K floats ≈ 7.9 MB << aggBytes (51.2 MB)

  int nb = (N + 255) / 256;

  hipMemsetAsync(cnt, 0, (size_t)N * sizeof(int), stream);

  const int* src = ei;
  const int* dst = ei + nE;

  int eb = (nE + 255) / 256;
  sge_count<<<eb, 256, 0, stream>>>(dst, cnt, nE);
  sge_blocksum<<<nb, 256, 0, stream>>>(cnt, bsum, N);
  sge_scan_top<<<1, 64, 0, stream>>>(bsum, offs, nb, N, nE);
  sge_scan_block<<<nb, 256, 0, stream>>>(cnt, bsum, offs, pos, N);
  sge_fill<<<eb, 256, 0, stream>>>(src, dst, pos, sorted_src, nE);

  sge_gemm<<<(N + 31) / 32, 256, 0, stream>>>(x, sorted_src, offs, W, z);

  sge_energy<<<nP, 256, 0, stream>>>(z, ep, en, partial, nP);
  sge_reduce<<<1, 1024, 0, stream>>>(partial, nP, 1.0f / (float)nP, out);
}